// Round 1
// baseline (718.320 us; speedup 1.0000x reference)
//
#include <hip/hip_runtime.h>

#define EPSF 1e-8f

typedef __attribute__((ext_vector_type(8))) short bf16x8;
typedef __attribute__((ext_vector_type(4))) float f32x4;

constexpr int Nv     = 10000;  // N
constexpr int Ne     = 5000;   // E
constexpr int Dd     = 128;    // d
constexpr int NPAD   = 10048;  // 157*64 (K-step is now 64)
constexpr int EPAD   = 5120;   // 40*128
constexpr int KSTEPS = 157;    // NPAD/64
constexpr int KSPLIT = 12;     // 40*12 = 480 blocks = one residency round at 2 blocks/CU

__device__ __forceinline__ unsigned short f2bf_rne(float f) {
    unsigned int u = __builtin_bit_cast(unsigned int, f);
    u += 0x7fffu + ((u >> 16) & 1u);
    return (unsigned short)(u >> 16);
}

// dvis[n] = (Dv[n,n]+eps)^-1/2 (0 in pad) — hoists 1.28M strided diag reads to 10048
__global__ void prep_dv_kernel(const float* __restrict__ Dv, float* __restrict__ dvis) {
    int n = blockIdx.x * 256 + threadIdx.x;
    if (n < NPAD) dvis[n] = (n < Nv) ? rsqrtf(Dv[(size_t)n * (Nv + 1)] + EPSF) : 0.0f;
}

// Fst[c][n] = bf16(F[n,c] * dvis[n]); n-contiguous rows (B-operand layout). Writes coalesced.
__global__ void prep_fst_kernel(const float* __restrict__ F, const float* __restrict__ dvis,
                                short* __restrict__ Fst) {
    int n = blockIdx.x * 256 + threadIdx.x;
    int c = blockIdx.y;
    if (n < NPAD) {
        unsigned short b = 0;
        if (n < Nv) b = f2bf_rne(F[(size_t)n * Dd + c] * dvis[n]);   // F L3-resident (5 MB)
        Fst[(size_t)c * NPAD + n] = (short)b;
    }
}

// sum(F*F) -> ws0[0]
__global__ void sum_ff_kernel(const float* __restrict__ F, float* __restrict__ out0) {
    const float4* F4 = (const float4*)F;
    int base = blockIdx.x * 512 + threadIdx.x;      // 625*512 = 320000 = N*d/4 exactly
    float4 a = F4[base];
    float4 b = F4[base + 256];
    float sum = a.x*a.x + a.y*a.y + a.z*a.z + a.w*a.w
              + b.x*b.x + b.y*b.y + b.z*b.z + b.w*b.w;
    #pragma unroll
    for (int off = 32; off; off >>= 1) sum += __shfl_down(sum, off);
    if ((threadIdx.x & 63) == 0) atomicAdd(out0, sum);
}

// Split-K GEMM: Mp[split][e][c] = sum_{n in split} H[n,e]*Fs[n,c]
// BK=64: 16 MFMA + 1 barrier per step (was 8 MFMA), 13-14 steps/split.
// 2-deep reg prefetch: writeLDS(step s) drains loads issued at step s-1 -> vmcnt wait
// has a full iteration of slack (HBM ~900cy fully covered).
__global__ __launch_bounds__(512, 4)
void gemm_split_kernel(const float* __restrict__ H, const short* __restrict__ Fst,
                       float* __restrict__ Mp) {
    // Alds[buf][e][kk]: row stride 36 u32 = 144 B (16B-aligned b128 frag reads;
    // 36 ≡ 4·odd mod 32 keeps staging writes at 2 lanes/bank = free, reads min-aliased)
    __shared__ unsigned int Alds[2][128 * 36];

    const int t   = threadIdx.x;
    const int w   = t >> 6;              // wave 0..7
    const int l   = t & 63;
    const int lm  = l & 15;
    const int q   = l >> 4;
    const int e0  = blockIdx.x * 128;
    const int we  = (w >> 1) * 32;       // wave e-offset {0,32,64,96}
    const int wc  = (w & 1) * 64;        // wave c-offset {0,64}
    const int spl = blockIdx.y;
    const int sb  = (spl * KSTEPS) / KSPLIT;
    const int se  = ((spl + 1) * KSTEPS) / KSPLIT;   // 13-14 steps/split

    const int rp  = t & 15;              // n-pair within 32-row half-chunk
    const int cpb = t >> 4;              // 0..31 col-pair base

    float2 hA[2][2][2], hB[2][2][2];     // [row-half jj][col-half j][row-in-pair]

    auto loadH = [&](int s, float2 (&h)[2][2][2]) {
        #pragma unroll
        for (int jj = 0; jj < 2; ++jj) {
            const int n = s * 64 + 32 * jj + 2 * rp;   // Nv even -> pair shares validity
            #pragma unroll
            for (int j = 0; j < 2; ++j) {
                const int e = e0 + 2 * (cpb + 32 * j); // Ne even -> pair shares validity
                h[jj][j][0] = make_float2(0.f, 0.f);
                h[jj][j][1] = make_float2(0.f, 0.f);
                if (n < Nv && e < Ne) {
                    h[jj][j][0] = *(const float2*)(H + (size_t)n * Ne + e);
                    h[jj][j][1] = *(const float2*)(H + (size_t)(n + 1) * Ne + e);
                }
            }
        }
    };
    auto writeLDS = [&](int buf, float2 (&h)[2][2][2]) {
        #pragma unroll
        for (int jj = 0; jj < 2; ++jj) {
            const int kp = rp + 16 * jj;               // n-pair index 0..31
            #pragma unroll
            for (int j = 0; j < 2; ++j) {
                const int el = 2 * (cpb + 32 * j);
                unsigned int w0 = (unsigned int)f2bf_rne(h[jj][j][0].x) | ((unsigned int)f2bf_rne(h[jj][j][1].x) << 16);
                unsigned int w1 = (unsigned int)f2bf_rne(h[jj][j][0].y) | ((unsigned int)f2bf_rne(h[jj][j][1].y) << 16);
                Alds[buf][el * 36 + kp]       = w0;    // row e,   kk = 2kp,2kp+1
                Alds[buf][(el + 1) * 36 + kp] = w1;    // row e+1
            }
        }
    };

    f32x4 acc[2][4];
    #pragma unroll
    for (int a = 0; a < 2; ++a)
        #pragma unroll
        for (int b = 0; b < 4; ++b) acc[a][b] = (f32x4){0.f, 0.f, 0.f, 0.f};

    // per-half compute: B frags direct from L2-hot Fst, A frags from LDS, 16 MFMA total
    auto compute = [&](int buf, int s) {
        #pragma unroll
        for (int h = 0; h < 2; ++h) {
            const int n0 = s * 64 + 32 * h + q * 8;
            bf16x8 Bf[4];
            #pragma unroll
            for (int cb = 0; cb < 4; ++cb) {
                const int c = wc + cb * 16 + lm;
                Bf[cb] = *(const bf16x8*)(Fst + (size_t)c * NPAD + n0);
            }
            bf16x8 Af[2];
            #pragma unroll
            for (int eb = 0; eb < 2; ++eb) {
                const int el = we + eb * 16 + lm;
                Af[eb] = *(const bf16x8*)((const char*)Alds[buf] + el * 144 + h * 64 + q * 16);
            }
            #pragma unroll
            for (int cb = 0; cb < 4; ++cb)
                #pragma unroll
                for (int eb = 0; eb < 2; ++eb)
                    acc[eb][cb] = __builtin_amdgcn_mfma_f32_16x16x32_bf16(
                        Af[eb], Bf[cb], acc[eb][cb], 0, 0, 0);
        }
    };

    // prologue: stage s=sb, hold s=sb+1 in hB
    loadH(sb, hA);
    writeLDS(0, hA);
    loadH(sb + 1, hB);
    __syncthreads();

    int s = sb, buf = 0;
    while (true) {
        // body A: issue s+2 -> hA (hA is free), stage s+1 from hB (loaded 1 iter ago)
        if (s + 2 < se) loadH(s + 2, hA);
        compute(buf, s);
        if (s + 1 < se) writeLDS(buf ^ 1, hB);
        __syncthreads();
        ++s; buf ^= 1;
        if (s >= se) break;

        // body B: roles swapped (manual unroll keeps all reg indices static)
        if (s + 2 < se) loadH(s + 2, hB);
        compute(buf, s);
        if (s + 1 < se) writeLDS(buf ^ 1, hA);
        __syncthreads();
        ++s; buf ^= 1;
        if (s >= se) break;
    }

    // epilogue: C/D layout col = lane&15, row = quad*4 + reg; plain coalesced stores
    float* dst = Mp + (size_t)spl * EPAD * 128;
    #pragma unroll
    for (int eb = 0; eb < 2; ++eb) {
        #pragma unroll
        for (int cb = 0; cb < 4; ++cb) {
            const int c = wc + cb * 16 + lm;
            #pragma unroll
            for (int r = 0; r < 4; ++r) {
                const int el = we + eb * 16 + q * 4 + r;
                dst[(size_t)(e0 + el) * 128 + c] = acc[eb][cb][r];
            }
        }
    }
}

// S = sum_e de_inv[e]*||sum_split Mp[.,e,:]||^2 -> ws0[1]  (de_inv folded in)
__global__ void reduce_m_kernel(const float* __restrict__ Mp, const float* __restrict__ De,
                                float* __restrict__ outS) {
    int gid = blockIdx.x * 256 + threadIdx.x;   // 640*256 = 163840 = EPAD*32
    int e   = gid >> 5;
    int c4  = (gid & 31) * 4;
    float de_inv = (e < Ne) ? 1.0f / (De[(size_t)e * (Ne + 1)] + EPSF) : 0.0f;  // wave-broadcast
    float4 m = {0.f, 0.f, 0.f, 0.f};
    #pragma unroll
    for (int sp = 0; sp < KSPLIT; ++sp) {
        float4 p = *(const float4*)(Mp + (size_t)sp * EPAD * 128 + (size_t)e * 128 + c4);
        m.x += p.x; m.y += p.y; m.z += p.z; m.w += p.w;
    }
    float sum = de_inv * (m.x*m.x + m.y*m.y + m.z*m.z + m.w*m.w);
    #pragma unroll
    for (int off = 32; off; off >>= 1) sum += __shfl_down(sum, off);
    if ((threadIdx.x & 63) == 0) atomicAdd(outS, sum);
}

__global__ void final_kernel(const float* __restrict__ ws0, float* __restrict__ out) {
    out[0] = (ws0[0] - ws0[1]) * (1.0f / (float)Nv);
}

extern "C" void kernel_launch(void* const* d_in, const int* in_sizes, int n_in,
                              void* d_out, int out_size, void* d_ws, size_t ws_size,
                              hipStream_t stream) {
    (void)in_sizes; (void)n_in; (void)out_size; (void)ws_size;
    const float* F  = (const float*)d_in[0];
    const float* H  = (const float*)d_in[1];
    const float* Dv = (const float*)d_in[2];
    const float* De = (const float*)d_in[3];
    float* out = (float*)d_out;

    // ws layout: ws0(16 f) | dvis[NPAD] | Mp[KSPLIT*EPAD*128] | Fst bf16[128*NPAD]
    float* ws0  = (float*)d_ws;
    float* dvis = ws0 + 16;
    float* Mp   = dvis + NPAD;                       // byte offset 40256 (16B-aligned)
    short* Fst  = (short*)(Mp + (size_t)KSPLIT * EPAD * 128);

    hipMemsetAsync(ws0, 0, 64, stream);              // only the two scalar accumulators

    prep_dv_kernel <<<(NPAD + 255) / 256, 256, 0, stream>>>(Dv, dvis);
    prep_fst_kernel<<<dim3((NPAD + 255) / 256, 128), 256, 0, stream>>>(F, dvis, Fst);
    sum_ff_kernel  <<<625, 256, 0, stream>>>(F, ws0);
    gemm_split_kernel<<<dim3(EPAD / 128, KSPLIT), 512, 0, stream>>>(H, Fst, Mp);
    reduce_m_kernel<<<640, 256, 0, stream>>>(Mp, De, ws0 + 1);
    final_kernel   <<<1, 1, 0, stream>>>(ws0, out);
}